// Round 6
// baseline (453.609 us; speedup 1.0000x reference)
//
#include <hip/hip_runtime.h>
#include <stdint.h>

#define N 2048
#define F 128
#define UDIM 128

typedef __attribute__((ext_vector_type(8))) __bf16 bf16x8;
typedef __attribute__((ext_vector_type(8))) unsigned short us8;
typedef __attribute__((ext_vector_type(4))) float f32x4;

__device__ __forceinline__ unsigned short f2bf(float f) {
  union { float f; uint32_t u; } v; v.f = f;
  uint32_t u = v.u;
  return (unsigned short)((u + 0x7FFFu + ((u >> 16) & 1u)) >> 16);
}
__device__ __forceinline__ float bf2f(unsigned short u) {
  union { uint32_t u; float f; } v; v.u = ((uint32_t)u) << 16; return v.f;
}
__device__ __forceinline__ uint32_t cvtpk(float lo, float hi) {
  uint32_t r;
  asm("v_cvt_pk_bf16_f32 %0, %1, %2" : "=v"(r) : "v"(lo), "v"(hi));
  return r;
}
__device__ __forceinline__ void async_load16(const void* g, void* l) {
  typedef const __attribute__((address_space(1))) uint32_t* gp_t;
  typedef __attribute__((address_space(3))) uint32_t* lp_t;
  __builtin_amdgcn_global_load_lds((gp_t)(uintptr_t)g, (lp_t)(uint32_t)(uintptr_t)l, 16, 0, 0);
}

// One cooperative kernel, 512 blocks (= 2/CU, all co-resident), 4 phases with
// device-atomic gating:
//   colsum half-shares (16 rows each, 1024 total; blocks 0-255 do 1, 256-511 do 3)
//   xwT: Z[b,u,i] = (X@W)[i,u] unscaled (block bid -> batch bid>>6, i0=(bid&63)*32)
//   scale (16 designates/batch): kcl + YT = kc_i * Z
//   gemm: out = relu(kc_i * (A@Y + qs*Y_i) + bias)   [R5 4-buffer pipeline]
__global__ __launch_bounds__(256, 2)
void gcn_fused(const float* __restrict__ A, const float* __restrict__ X,
               const float* __restrict__ W, const float* __restrict__ bias,
               const float* __restrict__ pptr, const float* __restrict__ qptr,
               float* __restrict__ out,
               float* __restrict__ partial, float* __restrict__ kcl,
               unsigned short* __restrict__ Z, unsigned short* __restrict__ YT,
               unsigned int* flags) {
  __shared__ __align__(16) unsigned char LDSRAW[81920];   // union of phase layouts

  unsigned int* ready = flags;       // [8], target 192 (128 colsum + 64 xwT)
  unsigned int* scnt  = flags + 8;   // [8], target 16

  const int bid = blockIdx.x;
  const int t = threadIdx.x;
  const int lane = t & 63;
  const int wid = t >> 6;
  const int b_own = bid >> 6;
  const int i0 = (bid & 63) << 5;

  // ---------------- phase 1a: colsum half-shares ----------------
  auto do_colsum = [&](int s) {
    const int b = s >> 7;
    const int rc = s & 127;                 // 16-row strip
    const float* ap = A + (size_t)b * N * N + (size_t)rc * 16 * N;
    const int j1 = t * 4, j2 = 1024 + t * 4;
    float4 a1 = {0.f, 0.f, 0.f, 0.f}, a2 = {0.f, 0.f, 0.f, 0.f};
    #pragma unroll 4
    for (int rr = 0; rr < 16; ++rr) {
      float4 v1 = *(const float4*)(ap + (size_t)rr * N + j1);
      float4 v2 = *(const float4*)(ap + (size_t)rr * N + j2);
      a1.x += v1.x; a1.y += v1.y; a1.z += v1.z; a1.w += v1.w;
      a2.x += v2.x; a2.y += v2.y; a2.z += v2.z; a2.w += v2.w;
    }
    float* pp = partial + ((size_t)b * 128 + rc) * N;
    *(float4*)(pp + j1) = a1;
    *(float4*)(pp + j2) = a2;
    __threadfence();
    __syncthreads();
    if (t == 0) atomicAdd(&ready[s >> 7], 1u);
  };

  if (bid < 256) {
    do_colsum(bid);                          // batches 0-1
  } else {
    const int base = bid - 256;
    #pragma unroll 1
    for (int k = 0; k < 3; ++k) do_colsum(256 + base + 256 * k);   // batches 2-7, batch-ordered
  }

  // ---------------- phase 1b: xwT (Z = (X@W)^T, unscaled) ----------------
  {
    unsigned short* Wl = (unsigned short*)LDSRAW;            // [128][128] swizzled, 32 KB
    unsigned short* Xl = (unsigned short*)(LDSRAW + 32768);  // [32][128] swizzled, 8 KB

    // stage W^T (bf16, swizzled)
    {
      const int u = t & 127;
      const int khalf = t >> 7;
      #pragma unroll
      for (int g = 0; g < 8; ++g) {
        const int k0 = khalf * 64 + g * 8;
        float v[8];
        #pragma unroll
        for (int e = 0; e < 8; ++e) v[e] = W[(size_t)(k0 + e) * 128 + u];
        uint4 w;
        w.x = cvtpk(v[0], v[1]); w.y = cvtpk(v[2], v[3]);
        w.z = cvtpk(v[4], v[5]); w.w = cvtpk(v[6], v[7]);
        const int slot = khalf * 8 + g;
        *(uint4*)&Wl[u * 128 + ((slot ^ (u & 7)) * 8)] = w;
      }
    }
    // stage X tile
    {
      const int r = t >> 3;
      const float* xp = X + ((size_t)b_own * N + i0 + r) * F + (t & 7) * 8;
      #pragma unroll
      for (int h = 0; h < 2; ++h) {
        float4 v0 = *(const float4*)(xp + h * 64);
        float4 v1 = *(const float4*)(xp + h * 64 + 4);
        uint4 w;
        w.x = cvtpk(v0.x, v0.y); w.y = cvtpk(v0.z, v0.w);
        w.z = cvtpk(v1.x, v1.y); w.w = cvtpk(v1.z, v1.w);
        const int slot = (t & 7) + h * 8;
        *(uint4*)&Xl[r * 128 + ((slot ^ (r & 7)) * 8)] = w;
      }
    }
    __syncthreads();

    f32x4 acc[2][2];
    #pragma unroll
    for (int a = 0; a < 2; ++a)
      #pragma unroll
      for (int c = 0; c < 2; ++c) { f32x4 z = {0.f, 0.f, 0.f, 0.f}; acc[a][c] = z; }

    const int u0 = wid * 32;
    #pragma unroll
    for (int kc = 0; kc < 4; ++kc) {
      bf16x8 af[2], bfv[2];
      #pragma unroll
      for (int ut = 0; ut < 2; ++ut) {
        const int u = u0 + ut * 16 + (lane & 15);
        const int sl = ((kc * 4 + (lane >> 4)) ^ (u & 7)) * 8;
        af[ut] = *(const bf16x8*)&Wl[u * 128 + sl];
      }
      #pragma unroll
      for (int it = 0; it < 2; ++it) {
        const int rr = it * 16 + (lane & 15);
        const int sl = ((kc * 4 + (lane >> 4)) ^ (rr & 7)) * 8;
        bfv[it] = *(const bf16x8*)&Xl[rr * 128 + sl];
      }
      #pragma unroll
      for (int ut = 0; ut < 2; ++ut)
        #pragma unroll
        for (int it = 0; it < 2; ++it)
          acc[ut][it] = __builtin_amdgcn_mfma_f32_16x16x32_bf16(af[ut], bfv[it], acc[ut][it], 0, 0, 0);
    }

    #pragma unroll
    for (int ut = 0; ut < 2; ++ut)
      #pragma unroll
      for (int it = 0; it < 2; ++it) {
        const int ic = i0 + it * 16 + (lane & 15);
        #pragma unroll
        for (int rg = 0; rg < 4; ++rg) {
          const int u = u0 + ut * 16 + (lane >> 4) * 4 + rg;
          Z[((size_t)b_own * UDIM + u) * N + ic] = f2bf(acc[ut][it][rg]);
        }
      }
    __threadfence();
    __syncthreads();
    if (t == 0) atomicAdd(&ready[b_own], 1u);
  }

  // ---------------- phase 2: scale (16 designated blocks per batch) ----------------
  if ((bid & 3) == 0) {
    if (t == 0) {
      while (__hip_atomic_load(&ready[b_own], __ATOMIC_ACQUIRE, __HIP_MEMORY_SCOPE_AGENT) < 192u)
        __builtin_amdgcn_s_sleep(8);
    }
    __syncthreads();
    __threadfence();

    float* red = (float*)LDSRAW;            // [2][128]
    float* kct = (float*)(LDSRAW + 1024);   // [128]
    const int ic = ((bid >> 2) & 15) * 128;
    {
      const int i = ic + (t & 127);
      const int half = t >> 7;
      float s = 0.f;
      #pragma unroll 8
      for (int rc = 0; rc < 64; ++rc)
        s += partial[((size_t)b_own * 128 + half * 64 + rc) * N + i];
      red[half * 128 + (t & 127)] = s;
    }
    __syncthreads();
    if (t < 128) {
      const float s = red[t] + red[128 + t];
      const float sp = 1.0f / (1.0f + __expf(-pptr[0]));
      const float k = sp + (1.0f - sp) * s;
      float rv = rsqrtf(sqrtf(k));          // k^(-0.25)
      if (isinf(rv)) rv = 0.f;
      kct[t] = rv;
      kcl[b_own * N + ic + t] = rv;
    }
    __syncthreads();
    {
      const int i8 = (t & 15) * 8;
      #pragma unroll
      for (int it = 0; it < 8; ++it) {
        const int u = it * 16 + (t >> 4);
        const size_t off = ((size_t)b_own * UDIM + u) * N + ic + i8;
        us8 z = *(const us8*)&Z[off];
        float y[8];
        #pragma unroll
        for (int e = 0; e < 8; ++e) y[e] = bf2f(z[e]) * kct[i8 + e];
        uint4 w;
        w.x = cvtpk(y[0], y[1]); w.y = cvtpk(y[2], y[3]);
        w.z = cvtpk(y[4], y[5]); w.w = cvtpk(y[6], y[7]);
        *(uint4*)&YT[off] = w;
      }
    }
    __threadfence();
    __syncthreads();
    if (t == 0) atomicAdd(&scnt[b_own], 1u);
  }

  // ---------------- phase 3: gemm ----------------
  if (t == 0) {
    while (__hip_atomic_load(&scnt[b_own], __ATOMIC_ACQUIRE, __HIP_MEMORY_SCOPE_AGENT) < 16u)
      __builtin_amdgcn_s_sleep(8);
  }
  __syncthreads();        // drains vm/lgkm for this wave (compiler-emitted full waitcnt)
  __threadfence();

  {
    unsigned short* Abuf = (unsigned short*)LDSRAW;            // 4 x 4 KB, swizzled
    unsigned short* Ybuf = (unsigned short*)(LDSRAW + 16384);  // 4 x 16 KB, swizzled

    const int wr = wid >> 1;
    const int wc = wid & 1;
    const int b = b_own;
    const float qs = 1.0f / (1.0f + __expf(-qptr[0]));

    const int r = t >> 3;
    const int c8 = t & 7;
    const float* Ap = A + (size_t)b * N * N + (size_t)(i0 + r) * N + c8 * 8;
    const unsigned short* YTb = YT + (size_t)b * UDIM * N;

    const int a_woff = r * 64 + ((c8 ^ (r & 7)) * 8);
    const int y_u = t >> 3;
    const int y_wavebase = (t & ~63) * 8;

    f32x4 acc[4];
    #pragma unroll
    for (int i = 0; i < 4; ++i) { f32x4 z = {0.f, 0.f, 0.f, 0.f}; acc[i] = z; }

    float4 a0A, a1A, a0B, a1B;

    auto issueY = [&](int kt, int buf) {
      const int k0 = kt * 64;
      #pragma unroll
      for (int rnd = 0; rnd < 4; ++rnd) {
        const int u = rnd * 32 + y_u;
        const int c16 = (t & 7) ^ (u & 7);
        async_load16(YTb + (size_t)u * N + k0 + c16 * 8, &Ybuf[buf * 8192 + rnd * 2048 + y_wavebase]);
      }
    };
    auto compute = [&](int cur) {
      const unsigned short* Ac = Abuf + cur * 2048;
      const unsigned short* Yc = Ybuf + cur * 8192;
      #pragma unroll
      for (int kk = 0; kk < 2; ++kk) {
        const int ar = 16 * wr + (lane & 15);
        const int as = ((kk * 4 + (lane >> 4)) ^ (ar & 7)) * 8;
        bf16x8 af = *(const bf16x8*)&Ac[ar * 64 + as];
        #pragma unroll
        for (int ut = 0; ut < 4; ++ut) {
          const int u = 64 * wc + ut * 16 + (lane & 15);
          const int bs = ((kk * 4 + (lane >> 4)) ^ (u & 7)) * 8;
          bf16x8 bfv = *(const bf16x8*)&Yc[u * 64 + bs];
          acc[ut] = __builtin_amdgcn_mfma_f32_16x16x32_bf16(af, bfv, acc[ut], 0, 0, 0);
        }
      }
    };

#define SB __builtin_amdgcn_sched_barrier(0)
#define ISSUE_A(KT, R0, R1) { R0 = *(const float4*)(Ap + (KT) * 64); R1 = *(const float4*)(Ap + (KT) * 64 + 4); }
#define CVT_A(BUF, R0, R1) { \
    uint4 w; w.x = cvtpk(R0.x, R0.y); w.y = cvtpk(R0.z, R0.w); \
    w.z = cvtpk(R1.x, R1.y); w.w = cvtpk(R1.z, R1.w); \
    *(uint4*)&Abuf[(BUF) * 2048 + a_woff] = w; }

    asm volatile("s_waitcnt vmcnt(0) lgkmcnt(0)" ::: "memory");  // clean queue for counted waits

    // prologue (queue order: A before Y each step)
    ISSUE_A(0, a0A, a1A); SB;
    ISSUE_A(1, a0B, a1B); SB;
    issueY(0, 0); SB;
    asm volatile("s_waitcnt vmcnt(6)" ::: "memory");
    CVT_A(0, a0A, a1A); SB;
    ISSUE_A(2, a0A, a1A); SB;
    issueY(1, 1); SB;
    asm volatile("s_waitcnt vmcnt(10)" ::: "memory");
    CVT_A(1, a0B, a1B); SB;
    ISSUE_A(3, a0B, a1B); SB;
    issueY(2, 2); SB;

#define GSTEP(KT, VM, R0, R1, DO_A, DO_Y)                          \
    {                                                              \
      asm volatile("s_waitcnt vmcnt(" #VM ")" ::: "memory");       \
      CVT_A(((KT) + 2) & 3, R0, R1);                               \
      asm volatile("s_waitcnt lgkmcnt(0)" ::: "memory");           \
      __builtin_amdgcn_s_barrier(); SB;                            \
      if (DO_A) { ISSUE_A((KT) + 4, R0, R1); } SB;                 \
      if (DO_Y) { issueY((KT) + 3, ((KT) + 3) & 3); } SB;          \
      __builtin_amdgcn_s_setprio(1);                               \
      compute((KT) & 3);                                           \
      __builtin_amdgcn_s_setprio(0); SB;                           \
    }

    #pragma unroll 1
    for (int kt = 0; kt < 28; kt += 2) {
      GSTEP(kt, 10, a0A, a1A, true, true);
      GSTEP(kt + 1, 10, a0B, a1B, true, true);
    }
    GSTEP(28, 10, a0A, a1A, false, true);
    GSTEP(29, 8, a0B, a1B, false, false);
    asm volatile("s_waitcnt vmcnt(4)" ::: "memory");
    __builtin_amdgcn_s_barrier(); SB;
    compute(2);
    asm volatile("s_waitcnt vmcnt(0)" ::: "memory");
    __builtin_amdgcn_s_barrier(); SB;
    compute(3);
#undef GSTEP
#undef CVT_A
#undef ISSUE_A
#undef SB

    // epilogue: diagonal qs*Y_i + row scale + bias + relu
    const int irow = i0 + 16 * wr + (lane >> 4) * 4;
    #pragma unroll
    for (int ut = 0; ut < 4; ++ut) {
      const int u = 64 * wc + ut * 16 + (lane & 15);
      const float bv = bias[u];
      #pragma unroll
      for (int rg = 0; rg < 4; ++rg) {
        const int i = irow + rg;
        const float yv = bf2f(YTb[(size_t)u * N + i]);
        const float kv = kcl[b * N + i];
        float vv = kv * (acc[ut][rg] + qs * yv) + bv;
        out[((size_t)b * N + i) * UDIM + u] = vv > 0.f ? vv : 0.f;
      }
    }
  }
}

extern "C" void kernel_launch(void* const* d_in, const int* in_sizes, int n_in,
                              void* d_out, int out_size, void* d_ws, size_t ws_size,
                              hipStream_t stream) {
  (void)in_sizes; (void)n_in; (void)out_size; (void)ws_size;
  const float* A    = (const float*)d_in[0];
  const float* X    = (const float*)d_in[1];
  const float* W    = (const float*)d_in[2];
  const float* bias = (const float*)d_in[3];
  const float* p    = (const float*)d_in[4];
  const float* q    = (const float*)d_in[5];
  float* out = (float*)d_out;

  char* ws = (char*)d_ws;
  unsigned int* flags = (unsigned int*)ws;                    // 64 B
  float* partial      = (float*)(ws + 4096);                  // [8][128][2048] f32 = 8 MB
  float* kcl          = (float*)(ws + 4096 + 8388608);        // 64 KB
  unsigned short* Zb  = (unsigned short*)(ws + 8458240);      // 4 MB
  unsigned short* YT  = (unsigned short*)(ws + 12652544);     // 4 MB

  hipMemsetAsync(flags, 0, 64, stream);

  void* args[] = {(void*)&A, (void*)&X, (void*)&W, (void*)&bias, (void*)&p, (void*)&q,
                  (void*)&out, (void*)&partial, (void*)&kcl, (void*)&Zb, (void*)&YT,
                  (void*)&flags};
  hipLaunchCooperativeKernel((const void*)gcn_fused, dim3(512), dim3(256), args, 0, stream);
}

// Round 7
// 213.664 us; speedup vs baseline: 2.1230x; 2.1230x over previous
//
#include <hip/hip_runtime.h>
#include <stdint.h>

#define N 2048
#define F 128
#define UDIM 128

typedef __attribute__((ext_vector_type(8))) __bf16 bf16x8;
typedef __attribute__((ext_vector_type(8))) unsigned short us8;
typedef __attribute__((ext_vector_type(4))) float f32x4;

__device__ __forceinline__ unsigned short f2bf(float f) {
  union { float f; uint32_t u; } v; v.f = f;
  uint32_t u = v.u;
  return (unsigned short)((u + 0x7FFFu + ((u >> 16) & 1u)) >> 16);
}
__device__ __forceinline__ float bf2f(unsigned short u) {
  union { uint32_t u; float f; } v; v.u = ((uint32_t)u) << 16; return v.f;
}
__device__ __forceinline__ uint32_t cvtpk(float lo, float hi) {
  uint32_t r;
  asm("v_cvt_pk_bf16_f32 %0, %1, %2" : "=v"(r) : "v"(lo), "v"(hi));
  return r;
}
__device__ __forceinline__ void async_load16(const void* g, void* l) {
  typedef const __attribute__((address_space(1))) uint32_t* gp_t;
  typedef __attribute__((address_space(3))) uint32_t* lp_t;
  __builtin_amdgcn_global_load_lds((gp_t)(uintptr_t)g, (lp_t)(uint32_t)(uintptr_t)l, 16, 0, 0);
}

// ================ kernel 1: colsum (blocks 0..1023, + last-finisher computes kcl)
//                  and Z=(X@W)^T unscaled (blocks 1024..1535) ================
__global__ __launch_bounds__(256, 4)
void gcn_pass1(const float* __restrict__ A, const float* __restrict__ X,
               const float* __restrict__ W, const float* __restrict__ pptr,
               float* __restrict__ partial, unsigned short* __restrict__ Z,
               float* __restrict__ kcl, unsigned int* __restrict__ tickets) {
  __shared__ __align__(16) unsigned char LDSRAW[40960];   // xwT: Wl 32KB + Xl 8KB; colsum: 4B flag

  const int bid = blockIdx.x;
  const int t = threadIdx.x;

  if (bid < 1024) {
    // ---- colsum role: partial[b][rc][j], 32 rows per block, half the columns ----
    const int b = bid >> 7;
    const int rc = (bid >> 1) & 63;
    const int j = (bid & 1) * 1024 + t * 4;
    const float* ap = A + (size_t)b * N * N + (size_t)rc * 32 * N + j;
    float s0 = 0.f, s1 = 0.f, s2 = 0.f, s3 = 0.f;
    #pragma unroll 4
    for (int rr = 0; rr < 32; ++rr) {
      float4 v = *(const float4*)(ap + (size_t)rr * N);
      s0 += v.x; s1 += v.y; s2 += v.z; s3 += v.w;
    }
    float4 s; s.x = s0; s.y = s1; s.z = s2; s.w = s3;
    *(float4*)&partial[((size_t)b * 64 + rc) * N + j] = s;

    // ticket: 128th finisher of batch b computes kcl[b] (no polling anywhere)
    unsigned int* lf = (unsigned int*)LDSRAW;
    __threadfence();
    __syncthreads();
    if (t == 0) {
      const unsigned int old = atomicAdd(&tickets[b * 32], 1u);   // 128B-padded counters
      *lf = (old == 127u) ? 1u : 0u;
    }
    __syncthreads();
    if (*lf) {
      __threadfence();
      const float sp = 1.0f / (1.0f + __expf(-pptr[0]));
      #pragma unroll 1
      for (int kq = 0; kq < 8; ++kq) {
        const int jj = kq * 256 + t;
        float s = 0.f;
        #pragma unroll 4
        for (int rc2 = 0; rc2 < 64; ++rc2)
          s += partial[((size_t)b * 64 + rc2) * N + jj];
        const float k = sp + (1.0f - sp) * s;
        float rv = rsqrtf(sqrtf(k));          // k^(-0.25)
        if (isinf(rv)) rv = 0.f;
        kcl[b * N + jj] = rv;
      }
    }
    return;
  }

  // ---- xwT role: Z[b,u,i] = (X@W)[i,u] unscaled ----
  const int zid = bid - 1024;
  const int lane = t & 63;
  const int wid = t >> 6;
  const int b = zid >> 6;
  const int i0 = (zid & 63) << 5;
  unsigned short* Wl = (unsigned short*)LDSRAW;            // [128][128] swizzled
  unsigned short* Xl = (unsigned short*)(LDSRAW + 32768);  // [32][128] swizzled

  {
    const int u = t & 127;
    const int khalf = t >> 7;
    #pragma unroll
    for (int g = 0; g < 8; ++g) {
      const int k0 = khalf * 64 + g * 8;
      float v[8];
      #pragma unroll
      for (int e = 0; e < 8; ++e) v[e] = W[(size_t)(k0 + e) * 128 + u];
      uint4 w;
      w.x = cvtpk(v[0], v[1]); w.y = cvtpk(v[2], v[3]);
      w.z = cvtpk(v[4], v[5]); w.w = cvtpk(v[6], v[7]);
      const int slot = khalf * 8 + g;
      *(uint4*)&Wl[u * 128 + ((slot ^ (u & 7)) * 8)] = w;
    }
  }
  {
    const int r = t >> 3;
    const float* xp = X + ((size_t)b * N + i0 + r) * F + (t & 7) * 8;
    #pragma unroll
    for (int h = 0; h < 2; ++h) {
      float4 v0 = *(const float4*)(xp + h * 64);
      float4 v1 = *(const float4*)(xp + h * 64 + 4);
      uint4 w;
      w.x = cvtpk(v0.x, v0.y); w.y = cvtpk(v0.z, v0.w);
      w.z = cvtpk(v1.x, v1.y); w.w = cvtpk(v1.z, v1.w);
      const int slot = (t & 7) + h * 8;
      *(uint4*)&Xl[r * 128 + ((slot ^ (r & 7)) * 8)] = w;
    }
  }
  __syncthreads();

  f32x4 acc[2][2];
  #pragma unroll
  for (int a = 0; a < 2; ++a)
    #pragma unroll
    for (int c = 0; c < 2; ++c) { f32x4 z = {0.f, 0.f, 0.f, 0.f}; acc[a][c] = z; }

  const int u0 = wid * 32;
  #pragma unroll
  for (int kc = 0; kc < 4; ++kc) {
    bf16x8 af[2], bfv[2];
    #pragma unroll
    for (int ut = 0; ut < 2; ++ut) {
      const int u = u0 + ut * 16 + (lane & 15);
      const int sl = ((kc * 4 + (lane >> 4)) ^ (u & 7)) * 8;
      af[ut] = *(const bf16x8*)&Wl[u * 128 + sl];
    }
    #pragma unroll
    for (int it = 0; it < 2; ++it) {
      const int rr = it * 16 + (lane & 15);
      const int sl = ((kc * 4 + (lane >> 4)) ^ (rr & 7)) * 8;
      bfv[it] = *(const bf16x8*)&Xl[rr * 128 + sl];
    }
    #pragma unroll
    for (int ut = 0; ut < 2; ++ut)
      #pragma unroll
      for (int it = 0; it < 2; ++it)
        acc[ut][it] = __builtin_amdgcn_mfma_f32_16x16x32_bf16(af[ut], bfv[it], acc[ut][it], 0, 0, 0);
  }

  #pragma unroll
  for (int ut = 0; ut < 2; ++ut)
    #pragma unroll
    for (int it = 0; it < 2; ++it) {
      const int ic = i0 + it * 16 + (lane & 15);
      #pragma unroll
      for (int rg = 0; rg < 4; ++rg) {
        const int u = u0 + ut * 16 + (lane >> 4) * 4 + rg;
        Z[((size_t)b * UDIM + u) * N + ic] = f2bf(acc[ut][it][rg]);
      }
    }
}

// ================ kernel 2: out = relu(kc_i * (A@(kc.*Z) + qs*kc_i*Z_i) + bias) ================
// kc_j folded into the A-operand during reg-staged fp32->bf16 conversion (kc tile in LDS).
// 3 LDS buffers; A issued 3 steps ahead (2 reg sets, index parity), Y 2 ahead; steady vmcnt(6).
__global__ __launch_bounds__(256, 2)
void gcn_gemm(const float* __restrict__ A, const unsigned short* __restrict__ Z,
              const float* __restrict__ kcl, const float* __restrict__ bias,
              const float* __restrict__ qptr, float* __restrict__ out) {
  __shared__ __align__(16) unsigned short Abuf[3 * 32 * 64];    // 12 KB, swizzled
  __shared__ __align__(16) unsigned short Ybuf[3 * 128 * 64];   // 48 KB, swizzled
  __shared__ __align__(16) float kcs[2048];                     // 8 KB

  const int t = threadIdx.x;
  const int lane = t & 63;
  const int wid = t >> 6;
  const int wr = wid >> 1;
  const int wc = wid & 1;

  const int bid = blockIdx.x;
  const int b = bid & 7;             // XCD-aware: batch b -> XCD b
  const int i0 = (bid >> 3) << 5;

  const float qs = 1.0f / (1.0f + __expf(-qptr[0]));

  const int r = t >> 3;
  const int c8 = t & 7;
  const float* Ap = A + (size_t)b * N * N + (size_t)(i0 + r) * N + c8 * 8;
  const unsigned short* Zb = Z + (size_t)b * UDIM * N;

  const int a_woff = r * 64 + ((c8 ^ (r & 7)) * 8);
  const int y_u = t >> 3;
  const int y_wavebase = (t & ~63) * 8;

  // stage kc tile (fp32, linear)
  {
    float4 v0 = *(const float4*)&kcl[b * N + t * 8];
    float4 v1 = *(const float4*)&kcl[b * N + t * 8 + 4];
    *(float4*)&kcs[t * 8] = v0;
    *(float4*)&kcs[t * 8 + 4] = v1;
  }
  __syncthreads();

  f32x4 acc[4];
  #pragma unroll
  for (int i = 0; i < 4; ++i) { f32x4 z = {0.f, 0.f, 0.f, 0.f}; acc[i] = z; }

  float4 a0A, a1A, a0B, a1B;   // reg set = K-tile index parity

  auto issueY = [&](int kt, int buf) {
    const int k0 = kt * 64;
    #pragma unroll
    for (int rnd = 0; rnd < 4; ++rnd) {
      const int u = rnd * 32 + y_u;
      const int c16 = (t & 7) ^ (u & 7);
      async_load16(Zb + (size_t)u * N + k0 + c16 * 8, &Ybuf[buf * 8192 + rnd * 2048 + y_wavebase]);
    }
  };
  auto compute = [&](int cur) {
    const unsigned short* Ac = Abuf + cur * 2048;
    const unsigned short* Yc = Ybuf + cur * 8192;
    #pragma unroll
    for (int kk = 0; kk < 2; ++kk) {
      const int ar = 16 * wr + (lane & 15);
      const int as = ((kk * 4 + (lane >> 4)) ^ (ar & 7)) * 8;
      bf16x8 af = *(const bf16x8*)&Ac[ar * 64 + as];
      #pragma unroll
      for (int ut = 0; ut < 4; ++ut) {
        const int u = 64 * wc + ut * 16 + (lane & 15);
        const int bs = ((kk * 4 + (lane >> 4)) ^ (u & 7)) * 8;
        bf16x8 bfv = *(const bf16x8*)&Yc[u * 64 + bs];
        acc[ut] = __builtin_amdgcn_mfma_f32_16x16x32_bf16(af, bfv, acc[ut], 0, 0, 0);
      }
    }
  };

#define SB __builtin_amdgcn_sched_barrier(0)
#define ISSUE_A(KT, R0, R1) { R0 = *(const float4*)(Ap + (KT) * 64); R1 = *(const float4*)(Ap + (KT) * 64 + 4); }
#define CVT_A(BUF, R0, R1, K0) { \
    float4 kj0 = *(const float4*)&kcs[(K0) + c8 * 8]; \
    float4 kj1 = *(const float4*)&kcs[(K0) + c8 * 8 + 4]; \
    uint4 w; \
    w.x = cvtpk(R0.x * kj0.x, R0.y * kj0.y); \
    w.y = cvtpk(R0.z * kj0.z, R0.w * kj0.w); \
    w.z = cvtpk(R1.x * kj1.x, R1.y * kj1.y); \
    w.w = cvtpk(R1.z * kj1.z, R1.w * kj1.w); \
    *(uint4*)&Abuf[(BUF) * 2048 + a_woff] = w; }

  asm volatile("s_waitcnt vmcnt(0) lgkmcnt(0)" ::: "memory");

  // ---- prologue ----
  ISSUE_A(0, a0A, a1A); SB;            // queue: A0(2)
  ISSUE_A(1, a0B, a1B); SB;            // A0 A1 (4)
  issueY(0, 0); SB;                    // A0 A1 Y0 (8)
  asm volatile("s_waitcnt vmcnt(6)" ::: "memory");   // retire A0
  CVT_A(0, a0A, a1A, 0); SB;
  ISSUE_A(2, a0A, a1A); SB;            // A1 Y0 A2 (8)
  issueY(1, 1); SB;                    // A1 Y0 A2 Y1 (12)

  // step kt: retire A(kt+1)+Y(kt) [vmcnt 6], convert A(kt+1)->buf (kt+1)%3,
  // barrier, issue A(kt+3) (same reg set), issue Y(kt+2), compute(kt).
#define GSTEP(KT, VM, R0, R1, DO_A, DO_Y)                          \
  {                                                                \
    asm volatile("s_waitcnt vmcnt(" #VM ")" ::: "memory");         \
    CVT_A(((KT) + 1) % 3, R0, R1, ((KT) + 1) * 64);                \
    asm volatile("s_waitcnt lgkmcnt(0)" ::: "memory");             \
    __builtin_amdgcn_s_barrier(); SB;                              \
    if (DO_A) { ISSUE_A((KT) + 3, R0, R1); } SB;                   \
    if (DO_Y) { issueY((KT) + 2, ((KT) + 2) % 3); } SB;            \
    __builtin_amdgcn_s_setprio(1);                                 \
    compute((KT) % 3);                                             \
    __builtin_amdgcn_s_setprio(0); SB;                             \
  }

  #pragma unroll 1
  for (int kt = 0; kt < 28; kt += 2) {
    GSTEP(kt,     6, a0B, a1B, true, true);     // reads A(kt+1) (odd -> set B)
    GSTEP(kt + 1, 6, a0A, a1A, true, true);     // reads A(kt+2) (even -> set A)
  }
  GSTEP(28, 6, a0B, a1B, true, true);           // reads A29, issues A31(setB)+Y30
  GSTEP(29, 6, a0A, a1A, false, true);          // reads A30, issues Y31
  // step 30: retire A31+Y30
  asm volatile("s_waitcnt vmcnt(4)" ::: "memory");
  CVT_A(1, a0B, a1B, 31 * 64);                  // A31 -> buf 31%3=1
  asm volatile("s_waitcnt lgkmcnt(0)" ::: "memory");
  __builtin_amdgcn_s_barrier(); SB;
  compute(0);                                   // kt=30 -> buf 0
  // step 31
  asm volatile("s_waitcnt vmcnt(0)" ::: "memory");
  __builtin_amdgcn_s_barrier(); SB;
  compute(1);
#undef GSTEP
#undef CVT_A
#undef ISSUE_A
#undef SB

  // epilogue: out = kc_i*acc + qs*kc_i^2*Z_i + bias, relu
  const int irow = i0 + 16 * wr + (lane >> 4) * 4;
  #pragma unroll
  for (int ut = 0; ut < 4; ++ut) {
    const int u = 64 * wc + ut * 16 + (lane & 15);
    const float bv = bias[u];
    #pragma unroll
    for (int rg = 0; rg < 4; ++rg) {
      const int i = irow + rg;
      const float zv = bf2f(Zb[(size_t)u * N + i]);
      const float kv = kcs[i];
      float vv = kv * acc[ut][rg] + qs * kv * kv * zv + bv;
      out[((size_t)b * N + i) * UDIM + u] = vv > 0.f ? vv : 0.f;
    }
  }
}

extern "C" void kernel_launch(void* const* d_in, const int* in_sizes, int n_in,
                              void* d_out, int out_size, void* d_ws, size_t ws_size,
                              hipStream_t stream) {
  (void)in_sizes; (void)n_in; (void)out_size; (void)ws_size;
  const float* A    = (const float*)d_in[0];
  const float* X    = (const float*)d_in[1];
  const float* W    = (const float*)d_in[2];
  const float* bias = (const float*)d_in[3];
  const float* p    = (const float*)d_in[4];
  const float* q    = (const float*)d_in[5];
  float* out = (float*)d_out;

  char* ws = (char*)d_ws;
  unsigned int* tickets = (unsigned int*)ws;                  // 8 counters, 128B apart
  float* partial        = (float*)(ws + 4096);                // [8][64][2048] f32 = 4 MB
  float* kcl            = (float*)(ws + 4096 + 4194304);      // 64 KB
  unsigned short* Zb    = (unsigned short*)(ws + 4096 + 4194304 + 65536);  // 4 MB

  hipMemsetAsync(tickets, 0, 1024, stream);
  gcn_pass1<<<dim3(1536), dim3(256), 0, stream>>>(A, X, W, p, partial, Zb, kcl, tickets);
  gcn_gemm<<<dim3(512), dim3(256), 0, stream>>>(A, Zb, kcl, bias, q, out);
}

// Round 8
// 57.336 us; speedup vs baseline: 7.9115x; 3.7265x over previous
//
#include <hip/hip_runtime.h>
#include <stdint.h>

#define N 2048
#define F 128
#define UDIM 128

typedef __attribute__((ext_vector_type(8))) __bf16 bf16x8;
typedef __attribute__((ext_vector_type(8))) unsigned short us8;
typedef __attribute__((ext_vector_type(4))) float f32x4;

__device__ __forceinline__ unsigned short f2bf(float f) {
  union { float f; uint32_t u; } v; v.f = f;
  uint32_t u = v.u;
  return (unsigned short)((u + 0x7FFFu + ((u >> 16) & 1u)) >> 16);
}
__device__ __forceinline__ float bf2f(unsigned short u) {
  union { uint32_t u; float f; } v; v.u = ((uint32_t)u) << 16; return v.f;
}
__device__ __forceinline__ uint32_t cvtpk(float lo, float hi) {
  uint32_t r;
  asm("v_cvt_pk_bf16_f32 %0, %1, %2" : "=v"(r) : "v"(lo), "v"(hi));
  return r;
}
__device__ __forceinline__ void async_load16(const void* g, void* l) {
  typedef const __attribute__((address_space(1))) uint32_t* gp_t;
  typedef __attribute__((address_space(3))) uint32_t* lp_t;
  __builtin_amdgcn_global_load_lds((gp_t)(uintptr_t)g, (lp_t)(uint32_t)(uintptr_t)l, 16, 0, 0);
}

// ================ kernel 1: [colsum blocks 0..1023] + [Z=(X@W)^T blocks 1024..1535] ================
// No fences, no atomics — kernel boundary is the release point.
__global__ __launch_bounds__(256, 4)
void gcn_pass1(const float* __restrict__ A, const float* __restrict__ X,
               const float* __restrict__ W, float* __restrict__ partial,
               unsigned short* __restrict__ Z) {
  __shared__ __align__(16) unsigned short Wl[128 * 128];  // [u][k] swizzled (xwT role only)
  __shared__ __align__(16) unsigned short Xl[32 * 128];   // [i][k] swizzled

  const int bid = blockIdx.x;
  const int t = threadIdx.x;

  if (bid < 1024) {
    // ---- colsum role: partial[b][rc][j], 32 rows per block ----
    const int b = bid >> 7;
    const int rc = (bid >> 1) & 63;
    const int j = (bid & 1) * 1024 + t * 4;
    const float* ap = A + (size_t)b * N * N + (size_t)rc * 32 * N + j;
    float s0 = 0.f, s1 = 0.f, s2 = 0.f, s3 = 0.f;
    #pragma unroll 4
    for (int rr = 0; rr < 32; ++rr) {
      float4 v = *(const float4*)(ap + (size_t)rr * N);
      s0 += v.x; s1 += v.y; s2 += v.z; s3 += v.w;
    }
    float4 s; s.x = s0; s.y = s1; s.z = s2; s.w = s3;
    *(float4*)&partial[((size_t)b * 64 + rc) * N + j] = s;
    return;
  }

  // ---- xwT role: Z[b,u,i] = (X@W)[i,u] (unscaled), computed transposed ----
  const int zid = bid - 1024;
  const int lane = t & 63;
  const int wid = t >> 6;
  const int b = zid >> 6;
  const int i0 = (zid & 63) << 5;

  // stage W^T into Wl[u][k] (swizzled)
  {
    const int u = t & 127;
    const int khalf = t >> 7;
    #pragma unroll
    for (int g = 0; g < 8; ++g) {
      const int k0 = khalf * 64 + g * 8;
      float v[8];
      #pragma unroll
      for (int e = 0; e < 8; ++e) v[e] = W[(size_t)(k0 + e) * 128 + u];
      uint4 w;
      w.x = cvtpk(v[0], v[1]); w.y = cvtpk(v[2], v[3]);
      w.z = cvtpk(v[4], v[5]); w.w = cvtpk(v[6], v[7]);
      const int slot = khalf * 8 + g;
      *(uint4*)&Wl[u * 128 + ((slot ^ (u & 7)) * 8)] = w;
    }
  }
  // stage X tile (fp32 -> bf16, swizzled)
  {
    const int r = t >> 3;
    const float* xp = X + ((size_t)b * N + i0 + r) * F + (t & 7) * 8;
    #pragma unroll
    for (int h = 0; h < 2; ++h) {
      float4 v0 = *(const float4*)(xp + h * 64);
      float4 v1 = *(const float4*)(xp + h * 64 + 4);
      uint4 w;
      w.x = cvtpk(v0.x, v0.y); w.y = cvtpk(v0.z, v0.w);
      w.z = cvtpk(v1.x, v1.y); w.w = cvtpk(v1.z, v1.w);
      const int slot = (t & 7) + h * 8;
      *(uint4*)&Xl[r * 128 + ((slot ^ (r & 7)) * 8)] = w;
    }
  }
  __syncthreads();

  f32x4 acc[2][2];
  #pragma unroll
  for (int a = 0; a < 2; ++a)
    #pragma unroll
    for (int c = 0; c < 2; ++c) { f32x4 z = {0.f, 0.f, 0.f, 0.f}; acc[a][c] = z; }

  const int u0 = wid * 32;
  #pragma unroll
  for (int kc = 0; kc < 4; ++kc) {
    bf16x8 af[2], bfv[2];
    #pragma unroll
    for (int ut = 0; ut < 2; ++ut) {
      const int u = u0 + ut * 16 + (lane & 15);
      const int sl = ((kc * 4 + (lane >> 4)) ^ (u & 7)) * 8;
      af[ut] = *(const bf16x8*)&Wl[u * 128 + sl];
    }
    #pragma unroll
    for (int it = 0; it < 2; ++it) {
      const int rr = it * 16 + (lane & 15);
      const int sl = ((kc * 4 + (lane >> 4)) ^ (rr & 7)) * 8;
      bfv[it] = *(const bf16x8*)&Xl[rr * 128 + sl];
    }
    #pragma unroll
    for (int ut = 0; ut < 2; ++ut)
      #pragma unroll
      for (int it = 0; it < 2; ++it)
        acc[ut][it] = __builtin_amdgcn_mfma_f32_16x16x32_bf16(af[ut], bfv[it], acc[ut][it], 0, 0, 0);
  }

  #pragma unroll
  for (int ut = 0; ut < 2; ++ut)
    #pragma unroll
    for (int it = 0; it < 2; ++it) {
      const int ic = i0 + it * 16 + (lane & 15);
      #pragma unroll
      for (int rg = 0; rg < 4; ++rg) {
        const int u = u0 + ut * 16 + (lane >> 4) * 4 + rg;
        Z[((size_t)b * UDIM + u) * N + ic] = f2bf(acc[ut][it][rg]);
      }
    }
}

// ================ kernel 2: kcl[b,j] = k^{-1/4} from partial (tiny, L2-resident) ================
// grid 64 (8 b x 8 chunks of 256), block 256.
__global__ __launch_bounds__(256, 4)
void gcn_kcl(const float* __restrict__ partial, const float* __restrict__ pptr,
             float* __restrict__ kcl) {
  const int t = threadIdx.x;
  const int b = blockIdx.x >> 3;
  const int jj = (blockIdx.x & 7) * 256 + t;
  float s = 0.f;
  #pragma unroll 8
  for (int rc = 0; rc < 64; ++rc)
    s += partial[((size_t)b * 64 + rc) * N + jj];
  const float sp = 1.0f / (1.0f + __expf(-pptr[0]));
  const float k = sp + (1.0f - sp) * s;
  float rv = rsqrtf(sqrtf(k));            // k^(-0.25)
  if (isinf(rv)) rv = 0.f;
  kcl[b * N + jj] = rv;
}

// ================ kernel 3: out = relu(kc_i * (A@(kc.*Z) + qs*kc_i*Z_i) + bias) ================
// kc_j folded into the A-operand during reg-staged fp32->bf16 conversion (kc tile in LDS).
// 3 LDS buffers; A issued 3 steps ahead (2 reg sets), Y 2 ahead; steady vmcnt(6).
__global__ __launch_bounds__(256, 2)
void gcn_gemm(const float* __restrict__ A, const unsigned short* __restrict__ Z,
              const float* __restrict__ kcl, const float* __restrict__ bias,
              const float* __restrict__ qptr, float* __restrict__ out) {
  __shared__ __align__(16) unsigned short Abuf[3 * 32 * 64];    // 12 KB, swizzled
  __shared__ __align__(16) unsigned short Ybuf[3 * 128 * 64];   // 48 KB, swizzled
  __shared__ __align__(16) float kcs[2048];                     // 8 KB

  const int t = threadIdx.x;
  const int lane = t & 63;
  const int wid = t >> 6;
  const int wr = wid >> 1;
  const int wc = wid & 1;

  const int bid = blockIdx.x;
  const int b = bid & 7;             // XCD-aware: batch b -> XCD b
  const int i0 = (bid >> 3) << 5;

  const float qs = 1.0f / (1.0f + __expf(-qptr[0]));

  const int r = t >> 3;
  const int c8 = t & 7;
  const float* Ap = A + (size_t)b * N * N + (size_t)(i0 + r) * N + c8 * 8;
  const unsigned short* Zb = Z + (size_t)b * UDIM * N;

  const int a_woff = r * 64 + ((c8 ^ (r & 7)) * 8);
  const int y_u = t >> 3;
  const int y_wavebase = (t & ~63) * 8;

  // stage kc tile (fp32, linear)
  {
    float4 v0 = *(const float4*)&kcl[b * N + t * 8];
    float4 v1 = *(const float4*)&kcl[b * N + t * 8 + 4];
    *(float4*)&kcs[t * 8] = v0;
    *(float4*)&kcs[t * 8 + 4] = v1;
  }
  __syncthreads();

  f32x4 acc[4];
  #pragma unroll
  for (int i = 0; i < 4; ++i) { f32x4 z = {0.f, 0.f, 0.f, 0.f}; acc[i] = z; }

  float4 a0A, a1A, a0B, a1B;   // reg set = K-tile index parity

  auto issueY = [&](int kt, int buf) {
    const int k0 = kt * 64;
    #pragma unroll
    for (int rnd = 0; rnd < 4; ++rnd) {
      const int u = rnd * 32 + y_u;
      const int c16 = (t & 7) ^ (u & 7);
      async_load16(Zb + (size_t)u * N + k0 + c16 * 8, &Ybuf[buf * 8192 + rnd * 2048 + y_wavebase]);
    }
  };
  auto compute = [&](int cur) {
    const unsigned short* Ac = Abuf + cur * 2048;
    const unsigned short* Yc = Ybuf + cur * 8192;
    #pragma unroll
    for (int kk = 0; kk < 2; ++kk) {
      const int ar = 16 * wr + (lane & 15);
      const int as = ((kk * 4 + (lane >> 4)) ^ (ar & 7)) * 8;
      bf16x8 af = *(const bf16x8*)&Ac[ar * 64 + as];
      #pragma unroll
      for (int ut = 0; ut < 4; ++ut) {
        const int u = 64 * wc + ut * 16 + (lane & 15);
        const int bs = ((kk * 4 + (lane >> 4)) ^ (u & 7)) * 8;
        bf16x8 bfv = *(const bf16x8*)&Yc[u * 64 + bs];
        acc[ut] = __builtin_amdgcn_mfma_f32_16x16x32_bf16(af, bfv, acc[ut], 0, 0, 0);
      }
    }
  };

#define SB __builtin_amdgcn_sched_barrier(0)
#define ISSUE_A(KT, R0, R1) { R0 = *(const float4*)(Ap + (KT) * 64); R1 = *(const float4*)(Ap + (KT) * 64 + 4); }
#define CVT_A(BUF, R0, R1, K0) { \
    float4 kj0 = *(const float4*)&kcs[(K0) + c8 * 8]; \
    float4 kj1 = *(const float4*)&kcs[(K0) + c8 * 8 + 4]; \
    uint4 w; \
    w.x = cvtpk(R0.x * kj0.x, R0.y * kj0.y); \
    w.y = cvtpk(R0.z * kj0.z, R0.w * kj0.w); \
    w.z = cvtpk(R1.x * kj1.x, R1.y * kj1.y); \
    w.w = cvtpk(R1.z * kj1.z, R1.w * kj1.w); \
    *(uint4*)&Abuf[(BUF) * 2048 + a_woff] = w; }

  asm volatile("s_waitcnt vmcnt(0) lgkmcnt(0)" ::: "memory");

  // ---- prologue ----
  ISSUE_A(0, a0A, a1A); SB;            // queue: A0(2)
  ISSUE_A(1, a0B, a1B); SB;            // A0 A1 (4)
  issueY(0, 0); SB;                    // A0 A1 Y0 (8)
  asm volatile("s_waitcnt vmcnt(6)" ::: "memory");   // retire A0
  CVT_A(0, a0A, a1A, 0); SB;
  ISSUE_A(2, a0A, a1A); SB;            // A1 Y0 A2 (8)
  issueY(1, 1); SB;                    // A1 Y0 A2 Y1 (12)

#define GSTEP(KT, VM, R0, R1, DO_A, DO_Y)                          \
  {                                                                \
    asm volatile("s_waitcnt vmcnt(" #VM ")" ::: "memory");         \
    CVT_A(((KT) + 1) % 3, R0, R1, ((KT) + 1) * 64);                \
    asm volatile("s_waitcnt lgkmcnt(0)" ::: "memory");             \
    __builtin_amdgcn_s_barrier(); SB;                              \
    if (DO_A) { ISSUE_A((KT) + 3, R0, R1); } SB;                   \
    if (DO_Y) { issueY((KT) + 2, ((KT) + 2) % 3); } SB;            \
    __builtin_amdgcn_s_setprio(1);                                 \
    compute((KT) % 3);                                             \
    __builtin_amdgcn_s_setprio(0); SB;                             \
  }

  #pragma unroll 1
  for (int kt = 0; kt < 28; kt += 2) {
    GSTEP(kt,     6, a0B, a1B, true, true);     // reads A(kt+1) (odd -> set B)
    GSTEP(kt + 1, 6, a0A, a1A, true, true);     // reads A(kt+2) (even -> set A)
  }
  GSTEP(28, 6, a0B, a1B, true, true);           // reads A29, issues A31(setB)+Y30
  GSTEP(29, 6, a0A, a1A, false, true);          // reads A30, issues Y31
  // step 30: retire A31+Y30
  asm volatile("s_waitcnt vmcnt(4)" ::: "memory");
  CVT_A(1, a0B, a1B, 31 * 64);                  // A31 -> buf 31%3=1
  asm volatile("s_waitcnt lgkmcnt(0)" ::: "memory");
  __builtin_amdgcn_s_barrier(); SB;
  compute(0);                                   // kt=30 -> buf 0
  // step 31
  asm volatile("s_waitcnt vmcnt(0)" ::: "memory");
  __builtin_amdgcn_s_barrier(); SB;
  compute(1);
#undef GSTEP
#undef CVT_A
#undef ISSUE_A
#undef SB

  // epilogue: out = kc_i*acc + qs*kc_i^2*Z_i + bias, relu
  const int irow = i0 + 16 * wr + (lane >> 4) * 4;
  #pragma unroll
  for (int ut = 0; ut < 4; ++ut) {
    const int u = 64 * wc + ut * 16 + (lane & 15);
    const float bv = bias[u];
    #pragma unroll
    for (int rg = 0; rg < 4; ++rg) {
      const int i = irow + rg;
      const float zv = bf2f(Zb[(size_t)u * N + i]);
      const float kv = kcs[i];
      float vv = kv * acc[ut][rg] + qs * kv * kv * zv + bv;
      out[((size_t)b * N + i) * UDIM + u] = vv > 0.f ? vv : 0.f;
    }
  }
}

extern "C" void kernel_launch(void* const* d_in, const int* in_sizes, int n_in,
                              void* d_out, int out_size, void* d_ws, size_t ws_size,
                              hipStream_t stream) {
  (void)in_sizes; (void)n_in; (void)out_size; (void)ws_size;
  const float* A    = (const float*)d_in[0];
  const float* X    = (const float*)d_in[1];
  const float* W    = (const float*)d_in[2];
  const float* bias = (const float*)d_in[3];
  const float* p    = (const float*)d_in[4];
  const float* q    = (const float*)d_in[5];
  float* out = (float*)d_out;

  char* ws = (char*)d_ws;
  float* partial      = (float*)ws;                          // [8][64][2048] f32 = 4 MB
  float* kcl          = (float*)(ws + 4194304);              // 64 KB
  unsigned short* Zb  = (unsigned short*)(ws + 4259840);     // 4 MB

  gcn_pass1<<<dim3(1536), dim3(256), 0, stream>>>(A, X, W, partial, Zb);
  gcn_kcl<<<dim3(64), dim3(256), 0, stream>>>(partial, p, kcl);
  gcn_gemm<<<dim3(512), dim3(256), 0, stream>>>(A, Zb, kcl, bias, q, out);
}